// Round 2
// baseline (1871.343 us; speedup 1.0000x reference)
//
#include <hip/hip_runtime.h>

// ---------------------------------------------------------------------------
// Decoder (show-and-tell style LSTM captioner), MI355X / gfx950.
// B=128, NP=196, FEAT=2048, E=512, D=512, V=10000, L=52, T=51.
// ALL external I/O is FLOAT32 (per reference dtypes). Internal compute uses
// bf16 MFMA with f32 accumulation (threshold 199.68 >> bf16 error ~1e-2).
//
// Pipeline:
//   prep        : sort lengths (stable desc), gather caps, nb[t], f32 outputs
//   feats_mean  : mean over 196 patches (f32 in, sorted) -> Xmean bf16
//   cast8       : word_w / w_hh f32 -> bf16 in ws (only if ws_size allows)
//   h0_kernel   : Hbf[0] = Xmean @ att1_w.T + att1_b          (MFMA)
//   xgates      : XG = emb[caps] @ w_ih.T + b_ih + b_hh       (MFMA, bf16 out)
//   chain_persist (x1): all 51 LSTM steps in ONE persistent kernel.
//                 64 blocks (co-resident on 256 CUs), device-scope atomic
//                 grid barrier between steps; c-state lives in registers.
//   pred        : out = Hbf[t+1] @ word_w.T + word_b (f32), prefix-masked
//
// XG (26.7 MB bf16) lives at the head of the d_out region (261 MB f32):
// consumed by all chain steps before pred_kernel overwrites the region.
// ---------------------------------------------------------------------------

typedef __attribute__((ext_vector_type(8))) short bf16x8;
typedef __attribute__((ext_vector_type(4))) float f32x4;

#define B_ 128
#define T_ 51
#define D_ 512
#define V_ 10000
#define FEAT_ 2048
#define NROW (T_ * B_)            // 6528
#define PRED_ELEMS (B_ * T_ * V_) // 65,280,000 floats

// ws layout (bytes)
#define HBF_OFF    0          // 52*128*512 bf16 = 6,815,744
#define BAR_OFF    6815744    // grid-barrier counter (64B reserved)
#define XMEAN_OFF  7077888    // 128*2048 bf16   =   524,288
#define CAPST_OFF  7602176    // 51*128 int      =    26,112
#define NB_OFF     7628288    // 64 int
#define SORT_OFF   7628544    // 128 int
#define SMALL_END  7629056    // ~7.3 MB minimal footprint
#define WORDBF_OFF 7629056    // 10000*512 bf16  = 10,240,000
#define WHHBF_OFF  17869056   // 2048*512 bf16   =  2,097,152
#define BIG_END    19966208   // ~19.0 MB with pre-cast weights

__device__ __forceinline__ float b2f(unsigned short u) {
    union { unsigned int i; float f; } v; v.i = ((unsigned int)u) << 16; return v.f;
}
__device__ __forceinline__ unsigned short f2b(float f) {
    union { float f; unsigned int i; } v; v.f = f;
    unsigned int r = v.i + 0x7FFFu + ((v.i >> 16) & 1u);
    return (unsigned short)(r >> 16);
}
__device__ __forceinline__ float sigmoid_(float x) { return 1.0f / (1.0f + __expf(-x)); }
__device__ __forceinline__ float tanh_(float x) {
    float ax = fabsf(x);
    float e = __expf(-2.0f * ax);
    float r = (1.0f - e) / (1.0f + e);
    return copysignf(r, x);
}

// fragment loaders: 8 consecutive k-elements -> bf16x8
__device__ __forceinline__ bf16x8 ldfrag(const unsigned short* p) {
    return *(const bf16x8*)p;
}
__device__ __forceinline__ bf16x8 ldfrag(const float* p) {
    f32x4 a = *(const f32x4*)p;
    f32x4 b = *(const f32x4*)(p + 4);
    bf16x8 r;
#pragma unroll
    for (int j = 0; j < 4; ++j) { r[j] = (short)f2b(a[j]); r[j + 4] = (short)f2b(b[j]); }
    return r;
}

// --------------------------------------------------------------------------
__global__ void prep_kernel(const int* __restrict__ caplen,
                            const int* __restrict__ caps_in,
                            int* __restrict__ capsT, int* __restrict__ nb,
                            int* __restrict__ sortind,
                            float* __restrict__ out_caps,
                            float* __restrict__ out_declen,
                            float* __restrict__ out_sortind) {
    __shared__ int s_len[B_], s_sort[B_], s_lens_s[B_];
    int b = threadIdx.x;
    int li = caplen[b];
    s_len[b] = li;
    __syncthreads();
    int rank = 0;
    for (int j = 0; j < B_; ++j) {
        int lj = s_len[j];
        rank += (lj > li) || (lj == li && j < b);  // stable descending
    }
    s_sort[rank] = b;
    __syncthreads();
    int ob = s_sort[b];
    sortind[b] = ob;
    out_sortind[b] = (float)ob;
    int ls = s_len[ob];
    s_lens_s[b] = ls;
    out_declen[b] = (float)(ls - 1);
    for (int l = 0; l < 52; ++l) {
        int tok = caps_in[ob * 52 + l];
        out_caps[b * 52 + l] = (float)tok;
        if (l < T_) capsT[l * B_ + b] = tok;
    }
    __syncthreads();
    if (b < T_) {
        int cnt = 0;
        for (int j = 0; j < B_; ++j) cnt += (s_lens_s[j] - 1 > b) ? 1 : 0;
        nb[b] = cnt;
    }
}

// --------------------------------------------------------------------------
// f32 -> bf16 bulk cast, 8 elems/thread
__global__ void cast8_kernel(const float* __restrict__ src,
                             unsigned short* __restrict__ dst, int n8) {
    int i = blockIdx.x * blockDim.x + threadIdx.x;
    if (i >= n8) return;
    *(bf16x8*)(dst + (size_t)i * 8) = ldfrag(src + (size_t)i * 8);
}

// --------------------------------------------------------------------------
// blocks (128 bs, 2 half) x 128 threads; thread owns 8 contiguous f32 cols.
__global__ void feats_mean_kernel(const float* __restrict__ feats,
                                  const int* __restrict__ sortind,
                                  unsigned short* __restrict__ xmean) {
    int bs = blockIdx.x;
    int ob = sortind[bs];
    int c8 = blockIdx.y * 1024 + threadIdx.x * 8;
    const float* base = feats + (size_t)ob * 196 * FEAT_ + c8;
    float acc[8];
#pragma unroll
    for (int j = 0; j < 8; ++j) acc[j] = 0.f;
    for (int p = 0; p < 196; ++p) {
        f32x4 a = *(const f32x4*)(base + (size_t)p * FEAT_);
        f32x4 b = *(const f32x4*)(base + (size_t)p * FEAT_ + 4);
#pragma unroll
        for (int j = 0; j < 4; ++j) { acc[j] += a[j]; acc[j + 4] += b[j]; }
    }
    const float inv = 1.0f / 196.0f;
    bf16x8 o;
#pragma unroll
    for (int j = 0; j < 8; ++j) o[j] = (short)f2b(acc[j] * inv);
    *(bf16x8*)(xmean + bs * FEAT_ + c8) = o;
}

// --------------------------------------------------------------------------
// Hbf[0] = Xmean(128x2048,bf16) @ att1_w(512x2048,f32).T + att1_b
__global__ void __launch_bounds__(256) h0_kernel(
    const unsigned short* __restrict__ xmean,
    const float* __restrict__ att1_w,
    const float* __restrict__ att1_b,
    unsigned short* __restrict__ hbf0) {
    int lane = threadIdx.x & 63;
    int gw = blockIdx.x * 4 + (threadIdx.x >> 6);  // 0..255
    int m0 = (gw >> 5) * 16;
    int n0 = (gw & 31) * 16;
    int kbase = (lane >> 4) * 8;
    const unsigned short* Ap = xmean + (m0 + (lane & 15)) * FEAT_ + kbase;
    const float* Bp = att1_w + (size_t)(n0 + (lane & 15)) * FEAT_ + kbase;
    f32x4 acc = {0.f, 0.f, 0.f, 0.f};
    for (int k = 0; k < FEAT_ / 32; ++k) {
        bf16x8 a = ldfrag(Ap + k * 32);
        bf16x8 b = ldfrag(Bp + k * 32);
        acc = __builtin_amdgcn_mfma_f32_16x16x32_bf16(a, b, acc, 0, 0, 0);
    }
    int n = n0 + (lane & 15);
    float bias = att1_b[n];
    int rbase = m0 + (lane >> 4) * 4;
#pragma unroll
    for (int r = 0; r < 4; ++r) hbf0[(rbase + r) * D_ + n] = f2b(acc[r] + bias);
}

// --------------------------------------------------------------------------
// XG[r][n] = emb[capsT[r]] @ w_ih.T + (b_ih+b_hh); 64x64 per wave; f32 srcs
__global__ void __launch_bounds__(256) xgates_kernel(
    const float* __restrict__ emb,
    const float* __restrict__ w_ih,
    const float* __restrict__ b_ih,
    const float* __restrict__ b_hh,
    const int* __restrict__ capsT, const int* __restrict__ nb,
    unsigned short* __restrict__ xg) {
    int r0 = blockIdx.x * 64;
    int t = r0 >> 7;
    int b0 = r0 & 127;
    if (b0 >= nb[t]) return;  // fully-masked rows never affect outputs
    int lane = threadIdx.x & 63;
    int w = threadIdx.x >> 6;
    int c0 = blockIdx.y * 256 + w * 64;
    int kbase = (lane >> 4) * 8;
    int nlo = lane & 15;
    const float* Ap[4];
    const float* Bp[4];
#pragma unroll
    for (int i = 0; i < 4; ++i) {
        int tok = capsT[r0 + i * 16 + nlo];
        Ap[i] = emb + (size_t)tok * D_ + kbase;
        Bp[i] = w_ih + (size_t)(c0 + i * 16 + nlo) * D_ + kbase;
    }
    f32x4 acc[4][4];
#pragma unroll
    for (int i = 0; i < 4; ++i)
#pragma unroll
        for (int j = 0; j < 4; ++j) acc[i][j] = (f32x4){0.f, 0.f, 0.f, 0.f};
    for (int k = 0; k < D_ / 32; ++k) {
        bf16x8 a[4], bb[4];
#pragma unroll
        for (int i = 0; i < 4; ++i) a[i] = ldfrag(Ap[i] + k * 32);
#pragma unroll
        for (int i = 0; i < 4; ++i) bb[i] = ldfrag(Bp[i] + k * 32);
#pragma unroll
        for (int im = 0; im < 4; ++im)
#pragma unroll
            for (int in = 0; in < 4; ++in)
                acc[im][in] = __builtin_amdgcn_mfma_f32_16x16x32_bf16(a[im], bb[in], acc[im][in], 0, 0, 0);
    }
    int qr = (lane >> 4) * 4;
#pragma unroll
    for (int in = 0; in < 4; ++in) {
        int n = c0 + in * 16 + nlo;
        float bias = b_ih[n] + b_hh[n];
#pragma unroll
        for (int im = 0; im < 4; ++im)
#pragma unroll
            for (int rr = 0; rr < 4; ++rr) {
                int r = r0 + im * 16 + qr + rr;
                xg[(size_t)r * 2048 + n] = f2b(acc[im][in][rr] + bias);
            }
    }
}

// --------------------------------------------------------------------------
// ALL 51 LSTM steps in one persistent kernel. 64 blocks x 256 threads
// (trivially co-resident on 256 CUs). Grid barrier = monotonic device-scope
// atomic counter (zeroed by hipMemsetAsync before launch). c-state lives in
// registers: each wave owns a fixed 16(m) x 16(n) tile across all steps.
// TB = ushort (pre-cast bf16 w_hh) or float (inline cvt fallback).
template <typename TB>
__global__ void __launch_bounds__(256) chain_persist_kernel(
    const TB* __restrict__ w_hh,
    const unsigned short* __restrict__ xg,
    unsigned short* __restrict__ hbf,
    int* __restrict__ bar) {
    int lane = threadIdx.x & 63;
    int gw = blockIdx.x * 4 + (threadIdx.x >> 6);  // 0..255
    int m0 = (gw >> 5) * 16;
    int n0 = (gw & 31) * 16;
    int kbase = (lane >> 4) * 8;
    int nlo = lane & 15;
    int qr = (lane >> 4) * 4;
    int n = n0 + nlo;
    const TB* Bp[4];
#pragma unroll
    for (int g = 0; g < 4; ++g)
        Bp[g] = w_hh + (size_t)(g * D_ + n0 + nlo) * D_ + kbase;
    float creg[4] = {0.f, 0.f, 0.f, 0.f};  // c for rows m0+qr+rr, col n

    for (int t = 0; t < T_; ++t) {
        const unsigned short* hin = hbf + (size_t)t * (B_ * D_);
        unsigned short* hout = hbf + (size_t)(t + 1) * (B_ * D_);
        const unsigned short* Ap = hin + (m0 + nlo) * D_ + kbase;
        f32x4 acc[4];
#pragma unroll
        for (int g = 0; g < 4; ++g) acc[g] = (f32x4){0.f, 0.f, 0.f, 0.f};
        for (int k = 0; k < D_ / 32; ++k) {
            bf16x8 a = ldfrag(Ap + k * 32);
#pragma unroll
            for (int g = 0; g < 4; ++g) {
                bf16x8 b = ldfrag(Bp[g] + k * 32);
                acc[g] = __builtin_amdgcn_mfma_f32_16x16x32_bf16(a, b, acc[g], 0, 0, 0);
            }
        }
        const unsigned short* xgr = xg + (size_t)t * B_ * 2048;
#pragma unroll
        for (int rr = 0; rr < 4; ++rr) {
            int m = m0 + qr + rr;
            const unsigned short* xrow = xgr + (size_t)m * 2048;
            float iv = sigmoid_(acc[0][rr] + b2f(xrow[n]));
            float fv = sigmoid_(acc[1][rr] + b2f(xrow[D_ + n]));
            float gv = tanh_(acc[2][rr] + b2f(xrow[2 * D_ + n]));
            float ov = sigmoid_(acc[3][rr] + b2f(xrow[3 * D_ + n]));
            float cn = fv * creg[rr] + iv * gv;
            creg[rr] = cn;
            hout[m * D_ + n] = f2b(ov * tanh_(cn));
        }
        // ---- grid barrier: release h[t+1] writes, acquire for next read ----
        __threadfence();            // agent-scope release (wb L2 to coherence pt)
        __syncthreads();
        if (threadIdx.x == 0) {
            __hip_atomic_fetch_add(bar, 1, __ATOMIC_RELEASE, __HIP_MEMORY_SCOPE_AGENT);
            int target = (t + 1) * (int)gridDim.x;
            while (__hip_atomic_load(bar, __ATOMIC_ACQUIRE, __HIP_MEMORY_SCOPE_AGENT) < target) {
                __builtin_amdgcn_s_sleep(1);
            }
        }
        __syncthreads();
        __threadfence();            // agent-scope acquire side (inv stale lines)
    }
}

// --------------------------------------------------------------------------
// preds(f32) = Hbf[t+1] @ word_w.T + word_b, prefix mask; 64x64 per wave
template <typename TB>
__global__ void __launch_bounds__(256) pred_kernel(
    const unsigned short* __restrict__ hbf,
    const TB* __restrict__ word_w,
    const float* __restrict__ word_b,
    const int* __restrict__ nb, float* __restrict__ out) {
    int lane = threadIdx.x & 63;
    int w = threadIdx.x >> 6;
    int r0 = blockIdx.x * 64;
    int t = r0 >> 7;
    int b0 = r0 & 127;
    int c0 = blockIdx.y * 256 + w * 64;
    int nbt = nb[t];
    if (b0 >= nbt) {  // fully masked: zero-fill this wave's 64x64 slice
        int cc = c0 + lane;
        if (cc < V_) {
            for (int rr = 0; rr < 64; ++rr)
                out[(size_t)(b0 + rr) * (T_ * V_) + (size_t)t * V_ + cc] = 0.f;
        }
        return;
    }
    int kbase = (lane >> 4) * 8;
    int nlo = lane & 15;
    const unsigned short* hrow = hbf + (size_t)(t + 1) * (B_ * D_);
    const unsigned short* Ap[4];
    const TB* Bp[4];
    int cvalid[4];
#pragma unroll
    for (int i = 0; i < 4; ++i) {
        Ap[i] = hrow + (size_t)(b0 + i * 16 + nlo) * D_ + kbase;
        int c = c0 + i * 16 + nlo;
        cvalid[i] = (c0 + i * 16) < V_;
        int cc = c < V_ ? c : (V_ - 1);
        Bp[i] = word_w + (size_t)cc * D_ + kbase;
    }
    f32x4 acc[4][4];
#pragma unroll
    for (int i = 0; i < 4; ++i)
#pragma unroll
        for (int j = 0; j < 4; ++j) acc[i][j] = (f32x4){0.f, 0.f, 0.f, 0.f};
    for (int k = 0; k < D_ / 32; ++k) {
        bf16x8 a[4], bb[4];
#pragma unroll
        for (int i = 0; i < 4; ++i) a[i] = ldfrag(Ap[i] + k * 32);
#pragma unroll
        for (int i = 0; i < 4; ++i) bb[i] = ldfrag(Bp[i] + k * 32);
#pragma unroll
        for (int im = 0; im < 4; ++im)
#pragma unroll
            for (int in = 0; in < 4; ++in)
                acc[im][in] = __builtin_amdgcn_mfma_f32_16x16x32_bf16(a[im], bb[in], acc[im][in], 0, 0, 0);
    }
    int qr = (lane >> 4) * 4;
#pragma unroll
    for (int in = 0; in < 4; ++in) {
        if (!cvalid[in]) continue;
        int c = c0 + in * 16 + nlo;
        float wb = word_b[c];
#pragma unroll
        for (int im = 0; im < 4; ++im)
#pragma unroll
            for (int rr = 0; rr < 4; ++rr) {
                int brow = b0 + im * 16 + qr + rr;
                float v = (brow < nbt) ? (acc[im][in][rr] + wb) : 0.0f;
                out[(size_t)brow * (T_ * V_) + (size_t)t * V_ + c] = v;
            }
    }
}

// --------------------------------------------------------------------------
extern "C" void kernel_launch(void* const* d_in, const int* in_sizes, int n_in,
                              void* d_out, int out_size, void* d_ws, size_t ws_size,
                              hipStream_t stream) {
    const float* feats = (const float*)d_in[0];
    const int* caps_in = (const int*)d_in[1];
    const int* caplen = (const int*)d_in[2];
    const float* emb = (const float*)d_in[3];
    const float* att1_w = (const float*)d_in[4];
    const float* att1_b = (const float*)d_in[5];
    const float* w_ih = (const float*)d_in[6];
    const float* w_hh = (const float*)d_in[7];
    const float* b_ih = (const float*)d_in[8];
    const float* b_hh = (const float*)d_in[9];
    const float* word_w = (const float*)d_in[10];
    const float* word_b = (const float*)d_in[11];
    float* out = (float*)d_out;
    (void)in_sizes; (void)n_in; (void)out_size;

    char* ws = (char*)d_ws;
    unsigned short* hbf = (unsigned short*)(ws + HBF_OFF);
    int* bar = (int*)(ws + BAR_OFF);
    unsigned short* xmean = (unsigned short*)(ws + XMEAN_OFF);
    int* capsT = (int*)(ws + CAPST_OFF);
    int* nb = (int*)(ws + NB_OFF);
    int* sortind = (int*)(ws + SORT_OFF);
    unsigned short* wordbf = (unsigned short*)(ws + WORDBF_OFF);
    unsigned short* whhbf = (unsigned short*)(ws + WHHBF_OFF);
    const bool big = ws_size >= (size_t)BIG_END;

    // XG (bf16) in the d_out region; fully consumed before pred overwrites.
    unsigned short* xg = (unsigned short*)d_out;

    float* out_caps = out + PRED_ELEMS;
    float* out_declen = out_caps + B_ * 52;
    float* out_sortind = out_declen + B_;

    hipMemsetAsync(bar, 0, 64, stream);  // grid-barrier counter
    prep_kernel<<<1, 128, 0, stream>>>(caplen, caps_in, capsT, nb, sortind,
                                       out_caps, out_declen, out_sortind);
    feats_mean_kernel<<<dim3(128, 2), 128, 0, stream>>>(feats, sortind, xmean);
    h0_kernel<<<64, 256, 0, stream>>>(xmean, att1_w, att1_b, hbf);
    if (big) {
        cast8_kernel<<<(640000 + 255) / 256, 256, 0, stream>>>(word_w, wordbf, 640000);
        cast8_kernel<<<(131072 + 255) / 256, 256, 0, stream>>>(w_hh, whhbf, 131072);
    }
    xgates_kernel<<<dim3(102, 8), 256, 0, stream>>>(emb, w_ih, b_ih, b_hh, capsT, nb, xg);
    if (big) {
        chain_persist_kernel<unsigned short><<<64, 256, 0, stream>>>(whhbf, xg, hbf, bar);
        pred_kernel<unsigned short><<<dim3(102, 40), 256, 0, stream>>>(hbf, wordbf, word_b, nb, out);
    } else {
        chain_persist_kernel<float><<<64, 256, 0, stream>>>(w_hh, xg, hbf, bar);
        pred_kernel<float><<<dim3(102, 40), 256, 0, stream>>>(hbf, word_w, word_b, nb, out);
    }
}

// Round 3
// 1435.937 us; speedup vs baseline: 1.3032x; 1.3032x over previous
//
#include <hip/hip_runtime.h>

// ---------------------------------------------------------------------------
// Decoder (show-and-tell style LSTM captioner), MI355X / gfx950.
// B=128, NP=196, FEAT=2048, E=512, D=512, V=10000, L=52, T=51.
// ALL external I/O is FLOAT32 (per reference dtypes). Internal compute uses
// bf16 MFMA with f32 accumulation (threshold 199.68 >> bf16 error ~1e-2).
//
// Pipeline:
//   prep        : sort lengths (stable desc), gather caps, nb[t], f32 outputs
//   feats_mean  : mean over 196 patches (f32 in, sorted) -> Xmean bf16
//   cast8       : word_w / w_hh f32 -> bf16 in ws (only if ws_size allows)
//   h0_kernel   : Hbf[0] = Xmean @ att1_w.T + att1_b          (MFMA)
//   xgates      : XG = emb[caps] @ w_ih.T + b_ih + b_hh       (MFMA, bf16 out)
//   chain_persist (x1): all 51 LSTM steps in ONE persistent kernel.
//                 64 blocks co-resident; h[t+1] is exchanged across XCDs via
//                 per-access write-through stores (sc0 sc1) + a RELAXED
//                 atomic barrier. NO bulk L2 flush/invalidate in the loop --
//                 w_hh stays L2-resident across all 51 steps. c-state in regs.
//   pred        : out = Hbf[t+1] @ word_w.T + word_b (f32), prefix-masked
//
// XG (26.7 MB bf16) lives at the head of the d_out region (261 MB f32):
// consumed by all chain steps before pred_kernel overwrites the region.
// ---------------------------------------------------------------------------

typedef __attribute__((ext_vector_type(8))) short bf16x8;
typedef __attribute__((ext_vector_type(4))) float f32x4;

#define B_ 128
#define T_ 51
#define D_ 512
#define V_ 10000
#define FEAT_ 2048
#define NROW (T_ * B_)            // 6528
#define PRED_ELEMS (B_ * T_ * V_) // 65,280,000 floats

// ws layout (bytes)
#define HBF_OFF    0          // 52*128*512 bf16 = 6,815,744
#define BAR_OFF    6815744    // grid-barrier counter (64B reserved)
#define XMEAN_OFF  7077888    // 128*2048 bf16   =   524,288
#define CAPST_OFF  7602176    // 51*128 int      =    26,112
#define NB_OFF     7628288    // 64 int
#define SORT_OFF   7628544    // 128 int
#define SMALL_END  7629056    // ~7.3 MB minimal footprint
#define WORDBF_OFF 7629056    // 10000*512 bf16  = 10,240,000
#define WHHBF_OFF  17869056   // 2048*512 bf16   =  2,097,152
#define BIG_END    19966208   // ~19.0 MB with pre-cast weights

__device__ __forceinline__ float b2f(unsigned short u) {
    union { unsigned int i; float f; } v; v.i = ((unsigned int)u) << 16; return v.f;
}
__device__ __forceinline__ unsigned short f2b(float f) {
    union { float f; unsigned int i; } v; v.f = f;
    unsigned int r = v.i + 0x7FFFu + ((v.i >> 16) & 1u);
    return (unsigned short)(r >> 16);
}
__device__ __forceinline__ float sigmoid_(float x) { return 1.0f / (1.0f + __expf(-x)); }
__device__ __forceinline__ float tanh_(float x) {
    float ax = fabsf(x);
    float e = __expf(-2.0f * ax);
    float r = (1.0f - e) / (1.0f + e);
    return copysignf(r, x);
}

// write-through (coherence-point) 16-bit store: cross-XCD visible without
// any bulk L2 writeback/invalidate. sc0 sc1 = system-scope flags on gfx950.
__device__ __forceinline__ void st_b16_wt(unsigned short* p, unsigned short v) {
    unsigned int vv = v;
    asm volatile("global_store_short %0, %1, off sc0 sc1"
                 :: "v"(p), "v"(vv) : "memory");
}

// fragment loaders: 8 consecutive k-elements -> bf16x8
__device__ __forceinline__ bf16x8 ldfrag(const unsigned short* p) {
    return *(const bf16x8*)p;
}
__device__ __forceinline__ bf16x8 ldfrag(const float* p) {
    f32x4 a = *(const f32x4*)p;
    f32x4 b = *(const f32x4*)(p + 4);
    bf16x8 r;
#pragma unroll
    for (int j = 0; j < 4; ++j) { r[j] = (short)f2b(a[j]); r[j + 4] = (short)f2b(b[j]); }
    return r;
}

// --------------------------------------------------------------------------
__global__ void prep_kernel(const int* __restrict__ caplen,
                            const int* __restrict__ caps_in,
                            int* __restrict__ capsT, int* __restrict__ nb,
                            int* __restrict__ sortind,
                            float* __restrict__ out_caps,
                            float* __restrict__ out_declen,
                            float* __restrict__ out_sortind) {
    __shared__ int s_len[B_], s_sort[B_], s_lens_s[B_];
    int b = threadIdx.x;
    int li = caplen[b];
    s_len[b] = li;
    __syncthreads();
    int rank = 0;
    for (int j = 0; j < B_; ++j) {
        int lj = s_len[j];
        rank += (lj > li) || (lj == li && j < b);  // stable descending
    }
    s_sort[rank] = b;
    __syncthreads();
    int ob = s_sort[b];
    sortind[b] = ob;
    out_sortind[b] = (float)ob;
    int ls = s_len[ob];
    s_lens_s[b] = ls;
    out_declen[b] = (float)(ls - 1);
    for (int l = 0; l < 52; ++l) {
        int tok = caps_in[ob * 52 + l];
        out_caps[b * 52 + l] = (float)tok;
        if (l < T_) capsT[l * B_ + b] = tok;
    }
    __syncthreads();
    if (b < T_) {
        int cnt = 0;
        for (int j = 0; j < B_; ++j) cnt += (s_lens_s[j] - 1 > b) ? 1 : 0;
        nb[b] = cnt;
    }
}

// --------------------------------------------------------------------------
// f32 -> bf16 bulk cast, 8 elems/thread
__global__ void cast8_kernel(const float* __restrict__ src,
                             unsigned short* __restrict__ dst, int n8) {
    int i = blockIdx.x * blockDim.x + threadIdx.x;
    if (i >= n8) return;
    *(bf16x8*)(dst + (size_t)i * 8) = ldfrag(src + (size_t)i * 8);
}

// --------------------------------------------------------------------------
// blocks (128 bs, 2 half) x 128 threads; thread owns 8 contiguous f32 cols.
__global__ void feats_mean_kernel(const float* __restrict__ feats,
                                  const int* __restrict__ sortind,
                                  unsigned short* __restrict__ xmean) {
    int bs = blockIdx.x;
    int ob = sortind[bs];
    int c8 = blockIdx.y * 1024 + threadIdx.x * 8;
    const float* base = feats + (size_t)ob * 196 * FEAT_ + c8;
    float acc[8];
#pragma unroll
    for (int j = 0; j < 8; ++j) acc[j] = 0.f;
    for (int p = 0; p < 196; ++p) {
        f32x4 a = *(const f32x4*)(base + (size_t)p * FEAT_);
        f32x4 b = *(const f32x4*)(base + (size_t)p * FEAT_ + 4);
#pragma unroll
        for (int j = 0; j < 4; ++j) { acc[j] += a[j]; acc[j + 4] += b[j]; }
    }
    const float inv = 1.0f / 196.0f;
    bf16x8 o;
#pragma unroll
    for (int j = 0; j < 8; ++j) o[j] = (short)f2b(acc[j] * inv);
    *(bf16x8*)(xmean + bs * FEAT_ + c8) = o;
}

// --------------------------------------------------------------------------
// Hbf[0] = Xmean(128x2048,bf16) @ att1_w(512x2048,f32).T + att1_b
__global__ void __launch_bounds__(256) h0_kernel(
    const unsigned short* __restrict__ xmean,
    const float* __restrict__ att1_w,
    const float* __restrict__ att1_b,
    unsigned short* __restrict__ hbf0) {
    int lane = threadIdx.x & 63;
    int gw = blockIdx.x * 4 + (threadIdx.x >> 6);  // 0..255
    int m0 = (gw >> 5) * 16;
    int n0 = (gw & 31) * 16;
    int kbase = (lane >> 4) * 8;
    const unsigned short* Ap = xmean + (m0 + (lane & 15)) * FEAT_ + kbase;
    const float* Bp = att1_w + (size_t)(n0 + (lane & 15)) * FEAT_ + kbase;
    f32x4 acc = {0.f, 0.f, 0.f, 0.f};
    for (int k = 0; k < FEAT_ / 32; ++k) {
        bf16x8 a = ldfrag(Ap + k * 32);
        bf16x8 b = ldfrag(Bp + k * 32);
        acc = __builtin_amdgcn_mfma_f32_16x16x32_bf16(a, b, acc, 0, 0, 0);
    }
    int n = n0 + (lane & 15);
    float bias = att1_b[n];
    int rbase = m0 + (lane >> 4) * 4;
#pragma unroll
    for (int r = 0; r < 4; ++r) hbf0[(rbase + r) * D_ + n] = f2b(acc[r] + bias);
}

// --------------------------------------------------------------------------
// XG[r][n] = emb[capsT[r]] @ w_ih.T + (b_ih+b_hh); 64x64 per wave; f32 srcs
__global__ void __launch_bounds__(256) xgates_kernel(
    const float* __restrict__ emb,
    const float* __restrict__ w_ih,
    const float* __restrict__ b_ih,
    const float* __restrict__ b_hh,
    const int* __restrict__ capsT, const int* __restrict__ nb,
    unsigned short* __restrict__ xg) {
    int r0 = blockIdx.x * 64;
    int t = r0 >> 7;
    int b0 = r0 & 127;
    if (b0 >= nb[t]) return;  // fully-masked rows never affect outputs
    int lane = threadIdx.x & 63;
    int w = threadIdx.x >> 6;
    int c0 = blockIdx.y * 256 + w * 64;
    int kbase = (lane >> 4) * 8;
    int nlo = lane & 15;
    const float* Ap[4];
    const float* Bp[4];
#pragma unroll
    for (int i = 0; i < 4; ++i) {
        int tok = capsT[r0 + i * 16 + nlo];
        Ap[i] = emb + (size_t)tok * D_ + kbase;
        Bp[i] = w_ih + (size_t)(c0 + i * 16 + nlo) * D_ + kbase;
    }
    f32x4 acc[4][4];
#pragma unroll
    for (int i = 0; i < 4; ++i)
#pragma unroll
        for (int j = 0; j < 4; ++j) acc[i][j] = (f32x4){0.f, 0.f, 0.f, 0.f};
    for (int k = 0; k < D_ / 32; ++k) {
        bf16x8 a[4], bb[4];
#pragma unroll
        for (int i = 0; i < 4; ++i) a[i] = ldfrag(Ap[i] + k * 32);
#pragma unroll
        for (int i = 0; i < 4; ++i) bb[i] = ldfrag(Bp[i] + k * 32);
#pragma unroll
        for (int im = 0; im < 4; ++im)
#pragma unroll
            for (int in = 0; in < 4; ++in)
                acc[im][in] = __builtin_amdgcn_mfma_f32_16x16x32_bf16(a[im], bb[in], acc[im][in], 0, 0, 0);
    }
    int qr = (lane >> 4) * 4;
#pragma unroll
    for (int in = 0; in < 4; ++in) {
        int n = c0 + in * 16 + nlo;
        float bias = b_ih[n] + b_hh[n];
#pragma unroll
        for (int im = 0; im < 4; ++im)
#pragma unroll
            for (int rr = 0; rr < 4; ++rr) {
                int r = r0 + im * 16 + qr + rr;
                xg[(size_t)r * 2048 + n] = f2b(acc[im][in][rr] + bias);
            }
    }
}

// --------------------------------------------------------------------------
// ALL 51 LSTM steps in one persistent kernel. 64 blocks x 256 threads
// (trivially co-resident). Cross-XCD h exchange via write-through sc0/sc1
// stores; h reads are plain cached loads (each h[t] range is never L2-filled
// before its write, so cached reads always miss -> fetch fresh from the
// coherence point; kernel-start acquire handles cross-replay staleness).
// Barrier: vmcnt-drain + RELAXED atomic add + RELAXED poll -- NO threadfence,
// so w_hh/xg stay L2-resident across all 51 steps.
template <typename TB>
__global__ void __launch_bounds__(256) chain_persist_kernel(
    const TB* __restrict__ w_hh,
    const unsigned short* __restrict__ xg,
    unsigned short* __restrict__ hbf,
    int* __restrict__ bar) {
    int lane = threadIdx.x & 63;
    int gw = blockIdx.x * 4 + (threadIdx.x >> 6);  // 0..255
    int m0 = (gw >> 5) * 16;
    int n0 = (gw & 31) * 16;
    int kbase = (lane >> 4) * 8;
    int nlo = lane & 15;
    int qr = (lane >> 4) * 4;
    int n = n0 + nlo;
    const TB* Bp[4];
#pragma unroll
    for (int g = 0; g < 4; ++g)
        Bp[g] = w_hh + (size_t)(g * D_ + n0 + nlo) * D_ + kbase;
    float creg[4] = {0.f, 0.f, 0.f, 0.f};  // c for rows m0+qr+rr, col n

    for (int t = 0; t < T_; ++t) {
        const unsigned short* hin = hbf + (size_t)t * (B_ * D_);
        unsigned short* hout = hbf + (size_t)(t + 1) * (B_ * D_);
        const unsigned short* Ap = hin + (m0 + nlo) * D_ + kbase;
        f32x4 acc[4];
#pragma unroll
        for (int g = 0; g < 4; ++g) acc[g] = (f32x4){0.f, 0.f, 0.f, 0.f};
        for (int k = 0; k < D_ / 32; ++k) {
            bf16x8 a = ldfrag(Ap + k * 32);
#pragma unroll
            for (int g = 0; g < 4; ++g) {
                bf16x8 b = ldfrag(Bp[g] + k * 32);
                acc[g] = __builtin_amdgcn_mfma_f32_16x16x32_bf16(a, b, acc[g], 0, 0, 0);
            }
        }
        const unsigned short* xgr = xg + (size_t)t * B_ * 2048;
#pragma unroll
        for (int rr = 0; rr < 4; ++rr) {
            int m = m0 + qr + rr;
            const unsigned short* xrow = xgr + (size_t)m * 2048;
            float iv = sigmoid_(acc[0][rr] + b2f(xrow[n]));
            float fv = sigmoid_(acc[1][rr] + b2f(xrow[D_ + n]));
            float gv = tanh_(acc[2][rr] + b2f(xrow[2 * D_ + n]));
            float ov = sigmoid_(acc[3][rr] + b2f(xrow[3 * D_ + n]));
            float cn = fv * creg[rr] + iv * gv;
            creg[rr] = cn;
            st_b16_wt(hout + m * D_ + n, f2b(ov * tanh_(cn)));  // write-through
        }
        if (t < T_ - 1) {
            // drain write-through stores to the coherence point, then signal.
            asm volatile("s_waitcnt vmcnt(0)" ::: "memory");
            __syncthreads();
            if (threadIdx.x == 0) {
                __hip_atomic_fetch_add(bar, 1, __ATOMIC_RELAXED, __HIP_MEMORY_SCOPE_AGENT);
                int target = (t + 1) * 64;
                while (__hip_atomic_load(bar, __ATOMIC_RELAXED, __HIP_MEMORY_SCOPE_AGENT) < target) {
                    __builtin_amdgcn_s_sleep(1);
                }
            }
            __syncthreads();
        }
    }
}

// --------------------------------------------------------------------------
// preds(f32) = Hbf[t+1] @ word_w.T + word_b, prefix mask; 64x64 per wave
template <typename TB>
__global__ void __launch_bounds__(256) pred_kernel(
    const unsigned short* __restrict__ hbf,
    const TB* __restrict__ word_w,
    const float* __restrict__ word_b,
    const int* __restrict__ nb, float* __restrict__ out) {
    int lane = threadIdx.x & 63;
    int w = threadIdx.x >> 6;
    int r0 = blockIdx.x * 64;
    int t = r0 >> 7;
    int b0 = r0 & 127;
    int c0 = blockIdx.y * 256 + w * 64;
    int nbt = nb[t];
    if (b0 >= nbt) {  // fully masked: zero-fill this wave's 64x64 slice
        int cc = c0 + lane;
        if (cc < V_) {
            for (int rr = 0; rr < 64; ++rr)
                out[(size_t)(b0 + rr) * (T_ * V_) + (size_t)t * V_ + cc] = 0.f;
        }
        return;
    }
    int kbase = (lane >> 4) * 8;
    int nlo = lane & 15;
    const unsigned short* hrow = hbf + (size_t)(t + 1) * (B_ * D_);
    const unsigned short* Ap[4];
    const TB* Bp[4];
    int cvalid[4];
#pragma unroll
    for (int i = 0; i < 4; ++i) {
        Ap[i] = hrow + (size_t)(b0 + i * 16 + nlo) * D_ + kbase;
        int c = c0 + i * 16 + nlo;
        cvalid[i] = (c0 + i * 16) < V_;
        int cc = c < V_ ? c : (V_ - 1);
        Bp[i] = word_w + (size_t)cc * D_ + kbase;
    }
    f32x4 acc[4][4];
#pragma unroll
    for (int i = 0; i < 4; ++i)
#pragma unroll
        for (int j = 0; j < 4; ++j) acc[i][j] = (f32x4){0.f, 0.f, 0.f, 0.f};
    for (int k = 0; k < D_ / 32; ++k) {
        bf16x8 a[4], bb[4];
#pragma unroll
        for (int i = 0; i < 4; ++i) a[i] = ldfrag(Ap[i] + k * 32);
#pragma unroll
        for (int i = 0; i < 4; ++i) bb[i] = ldfrag(Bp[i] + k * 32);
#pragma unroll
        for (int im = 0; im < 4; ++im)
#pragma unroll
            for (int in = 0; in < 4; ++in)
                acc[im][in] = __builtin_amdgcn_mfma_f32_16x16x32_bf16(a[im], bb[in], acc[im][in], 0, 0, 0);
    }
    int qr = (lane >> 4) * 4;
#pragma unroll
    for (int in = 0; in < 4; ++in) {
        if (!cvalid[in]) continue;
        int c = c0 + in * 16 + nlo;
        float wb = word_b[c];
#pragma unroll
        for (int im = 0; im < 4; ++im)
#pragma unroll
            for (int rr = 0; rr < 4; ++rr) {
                int brow = b0 + im * 16 + qr + rr;
                float v = (brow < nbt) ? (acc[im][in][rr] + wb) : 0.0f;
                out[(size_t)brow * (T_ * V_) + (size_t)t * V_ + c] = v;
            }
    }
}

// --------------------------------------------------------------------------
extern "C" void kernel_launch(void* const* d_in, const int* in_sizes, int n_in,
                              void* d_out, int out_size, void* d_ws, size_t ws_size,
                              hipStream_t stream) {
    const float* feats = (const float*)d_in[0];
    const int* caps_in = (const int*)d_in[1];
    const int* caplen = (const int*)d_in[2];
    const float* emb = (const float*)d_in[3];
    const float* att1_w = (const float*)d_in[4];
    const float* att1_b = (const float*)d_in[5];
    const float* w_ih = (const float*)d_in[6];
    const float* w_hh = (const float*)d_in[7];
    const float* b_ih = (const float*)d_in[8];
    const float* b_hh = (const float*)d_in[9];
    const float* word_w = (const float*)d_in[10];
    const float* word_b = (const float*)d_in[11];
    float* out = (float*)d_out;
    (void)in_sizes; (void)n_in; (void)out_size;

    char* ws = (char*)d_ws;
    unsigned short* hbf = (unsigned short*)(ws + HBF_OFF);
    int* bar = (int*)(ws + BAR_OFF);
    unsigned short* xmean = (unsigned short*)(ws + XMEAN_OFF);
    int* capsT = (int*)(ws + CAPST_OFF);
    int* nb = (int*)(ws + NB_OFF);
    int* sortind = (int*)(ws + SORT_OFF);
    unsigned short* wordbf = (unsigned short*)(ws + WORDBF_OFF);
    unsigned short* whhbf = (unsigned short*)(ws + WHHBF_OFF);
    const bool big = ws_size >= (size_t)BIG_END;

    // XG (bf16) in the d_out region; fully consumed before pred overwrites.
    unsigned short* xg = (unsigned short*)d_out;

    float* out_caps = out + PRED_ELEMS;
    float* out_declen = out_caps + B_ * 52;
    float* out_sortind = out_declen + B_;

    hipMemsetAsync(bar, 0, 64, stream);  // grid-barrier counter
    prep_kernel<<<1, 128, 0, stream>>>(caplen, caps_in, capsT, nb, sortind,
                                       out_caps, out_declen, out_sortind);
    feats_mean_kernel<<<dim3(128, 2), 128, 0, stream>>>(feats, sortind, xmean);
    h0_kernel<<<64, 256, 0, stream>>>(xmean, att1_w, att1_b, hbf);
    if (big) {
        cast8_kernel<<<(640000 + 255) / 256, 256, 0, stream>>>(word_w, wordbf, 640000);
        cast8_kernel<<<(131072 + 255) / 256, 256, 0, stream>>>(w_hh, whhbf, 131072);
    }
    xgates_kernel<<<dim3(102, 8), 256, 0, stream>>>(emb, w_ih, b_ih, b_hh, capsT, nb, xg);
    if (big) {
        chain_persist_kernel<unsigned short><<<64, 256, 0, stream>>>(whhbf, xg, hbf, bar);
        pred_kernel<unsigned short><<<dim3(102, 40), 256, 0, stream>>>(hbf, wordbf, word_b, nb, out);
    } else {
        chain_persist_kernel<float><<<64, 256, 0, stream>>>(w_hh, xg, hbf, bar);
        pred_kernel<float><<<dim3(102, 40), 256, 0, stream>>>(hbf, word_w, word_b, nb, out);
    }
}